// Round 1
// baseline (526.635 us; speedup 1.0000x reference)
//
#include <hip/hip_runtime.h>
#include <math.h>

// Problem constants
#define BB 4
#define CC 128
#define C8 16
#define TEXTN 256
#define NN 4096     // D*H*W = 16^3
#define QB 64       // query tile
#define KB 64       // key tile

// workspace layout (in floats):
//   tkv : [B][144]          at 0        (16 tk + 128 tv per batch)
//   qt  : [B][N][16]        at 1024
//   kt  : [B][N][16]        at 1024 + B*N*16
//   vt  : [B][N][128]       at 1024 + 2*B*N*16
// total = 1024 + 2*262144 + 2097152 floats = ~10.5 MB

// ---------------------------------------------------------------------------
// Kernel 1: text-conditioned additive k/v bias: tk = Wtk@text + btk, tv = ...
__global__ __launch_bounds__(256) void k_text(
    const float* __restrict__ text, const float* __restrict__ Wtk,
    const float* __restrict__ btk, const float* __restrict__ Wtv,
    const float* __restrict__ btv, float* __restrict__ tkv) {
  __shared__ float ts[TEXTN];
  int b = blockIdx.x;
  for (int i = threadIdx.x; i < TEXTN; i += 256) ts[i] = text[b * TEXTN + i];
  __syncthreads();
  int o = threadIdx.x;
  if (o < 144) {
    const float* w;
    float acc;
    if (o < 16) { w = Wtk + o * TEXTN; acc = btk[o]; }
    else        { w = Wtv + (o - 16) * TEXTN; acc = btv[o - 16]; }
    #pragma unroll 8
    for (int t = 0; t < TEXTN; t++) acc += w[t] * ts[t];
    tkv[b * 144 + o] = acc;
  }
}

// ---------------------------------------------------------------------------
// Kernel 2: 1x1x1 conv projections. Per block: 64 voxels of one batch.
// Writes qt[b][n][16], kt[b][n][16] (+bk+tk), vt[b][n][128] (+bv+tv).
__global__ __launch_bounds__(256) void k_qkv(
    const float* __restrict__ x,
    const float* __restrict__ Wq, const float* __restrict__ bq,
    const float* __restrict__ Wk, const float* __restrict__ bk,
    const float* __restrict__ Wv, const float* __restrict__ bv,
    const float* __restrict__ tkv,
    float* __restrict__ qt, float* __restrict__ kt, float* __restrict__ vt) {
  __shared__ __align__(16) float xs[CC][64];  // 32 KB, [channel][voxel]
  int b = blockIdx.x >> 6;
  int n0 = (blockIdx.x & 63) * 64;
  int t = threadIdx.x;
  // stage x tile: rows of x are contiguous over n -> coalesced float4
  const float4* xg = (const float4*)(x + (size_t)b * CC * NN + n0);
  for (int i = t; i < CC * 64 / 4; i += 256) {
    int c = i >> 4, n4 = i & 15;
    ((float4*)xs)[c * 16 + n4] = xg[c * (NN / 4) + n4];
  }
  __syncthreads();
  // 160 output channels (16 q + 16 k + 128 v) x 64 voxels
  for (int idx = t; idx < 160 * 64; idx += 256) {
    int o = idx >> 6, nl = idx & 63;  // o is wave-uniform -> scalar weight loads
    const float* w;
    float acc;
    int kind, oo;
    if (o < 16)      { oo = o;      w = Wq + oo * CC; acc = bq[oo]; kind = 0; }
    else if (o < 32) { oo = o - 16; w = Wk + oo * CC; acc = bk[oo] + tkv[b * 144 + oo]; kind = 1; }
    else             { oo = o - 32; w = Wv + oo * CC; acc = bv[oo] + tkv[b * 144 + 16 + oo]; kind = 2; }
    #pragma unroll 8
    for (int c = 0; c < CC; c++) acc += w[c] * xs[c][nl];
    int n = n0 + nl;
    if (kind == 0)      qt[((size_t)b * NN + n) * C8 + oo] = acc;
    else if (kind == 1) kt[((size_t)b * NN + n) * C8 + oo] = acc;
    else                vt[((size_t)b * NN + n) * CC + oo] = acc;
  }
}

// ---------------------------------------------------------------------------
// Kernel 3: flash attention. One block per (batch, 64-query tile).
// Online softmax over 64 key tiles of 64 keys.
__global__ __launch_bounds__(256) void k_attn(
    const float* __restrict__ qt, const float* __restrict__ kt,
    const float* __restrict__ vt, const float* __restrict__ x,
    const float* __restrict__ gamma_p, float* __restrict__ out) {
  __shared__ __align__(16) float Ks[KB][C8];   // 4 KB
  __shared__ __align__(16) float Vs[KB][CC];   // 32 KB
  __shared__ __align__(16) float ST[KB][68];   // 17 KB, scores/p transposed [m][q]
  __shared__ __align__(16) float CorrS[QB];    // per-q rescale factor / final l

  int b = blockIdx.x >> 6;
  int q0 = (blockIdx.x & 63) * QB;
  int t = threadIdx.x;

  // phase identities
  int qa = t & 63;   // phase A: score row
  int mg = t >> 6;   //          key sub-group (0..3)
  int qb = t >> 2;   // phase B: softmax row
  int cc = t & 3;    //          m-split lane (0..3)
  int qg = t >> 4;   // phase C: q-group (0..15), q = qg*4+jj
  int cg = t & 15;   //          c-group (0..15), c = cg*8+i

  // Q row for this thread's phase-A role, held in registers the whole kernel
  float qreg[C8];
  {
    const float4* qrow = (const float4*)(qt + ((size_t)b * NN + q0 + qa) * C8);
    #pragma unroll
    for (int i = 0; i < 4; i++) {
      float4 v = qrow[i];
      qreg[4 * i + 0] = v.x; qreg[4 * i + 1] = v.y;
      qreg[4 * i + 2] = v.z; qreg[4 * i + 3] = v.w;
    }
  }

  float m_run = -INFINITY, l_run = 0.f;  // phase-B state for row qb
  float acc[4][8];                       // phase-C accumulator [jj][i]
  #pragma unroll
  for (int j = 0; j < 4; j++)
    #pragma unroll
    for (int i = 0; i < 8; i++) acc[j][i] = 0.f;

  for (int kb = 0; kb < NN / KB; kb++) {
    int m0 = kb * KB;
    // ---- load K and V tiles (coalesced float4) ----
    {
      const float4* kg = (const float4*)(kt + ((size_t)b * NN + m0) * C8);
      for (int i = t; i < KB * C8 / 4; i += 256) ((float4*)Ks)[i] = kg[i];
      const float4* vg = (const float4*)(vt + ((size_t)b * NN + m0) * CC);
      for (int i = t; i < KB * CC / 4; i += 256) ((float4*)Vs)[i] = vg[i];
    }
    __syncthreads();

    // ---- phase A: scores s[m][qa] = q[qa] . k[m] ----
    #pragma unroll
    for (int j = 0; j < 16; j++) {
      int m = mg * 16 + j;  // wave-uniform -> Ks row broadcast
      float s = 0.f;
      #pragma unroll
      for (int o = 0; o < C8; o++) s += qreg[o] * Ks[m][o];
      ST[m][qa] = s;
    }
    __syncthreads();

    // ---- phase B: online softmax for row qb (4 lanes split m) ----
    {
      float sv[16];
      float mx = -INFINITY;
      #pragma unroll
      for (int j = 0; j < 16; j++) {
        sv[j] = ST[4 * j + cc][qb];
        mx = fmaxf(mx, sv[j]);
      }
      mx = fmaxf(mx, __shfl_xor(mx, 1));
      mx = fmaxf(mx, __shfl_xor(mx, 2));
      float new_m = fmaxf(m_run, mx);
      float corr = __expf(m_run - new_m);  // expf(-inf)=0 on first tile
      float psum = 0.f;
      #pragma unroll
      for (int j = 0; j < 16; j++) {
        float p = __expf(sv[j] - new_m);
        psum += p;
        ST[4 * j + cc][qb] = p;  // each thread rewrites only slots it read
      }
      psum += __shfl_xor(psum, 1);
      psum += __shfl_xor(psum, 2);
      l_run = l_run * corr + psum;
      m_run = new_m;
      if (cc == 0) CorrS[qb] = corr;
    }
    __syncthreads();

    // ---- phase C: acc = acc*corr + P^T V for tile ----
    {
      const float4 cv = *(const float4*)&CorrS[qg * 4];
      float corr4[4] = {cv.x, cv.y, cv.z, cv.w};
      #pragma unroll
      for (int j = 0; j < 4; j++)
        #pragma unroll
        for (int i = 0; i < 8; i++) acc[j][i] *= corr4[j];
      #pragma unroll 4
      for (int m = 0; m < KB; m++) {
        float4 p4 = *(const float4*)&ST[m][qg * 4];
        float4 va = *(const float4*)&Vs[m][cg * 8];
        float4 vb = *(const float4*)&Vs[m][cg * 8 + 4];
        float pj[4] = {p4.x, p4.y, p4.z, p4.w};
        float vv[8] = {va.x, va.y, va.z, va.w, vb.x, vb.y, vb.z, vb.w};
        #pragma unroll
        for (int j = 0; j < 4; j++)
          #pragma unroll
          for (int i = 0; i < 8; i++) acc[j][i] += pj[j] * vv[i];
      }
    }
    __syncthreads();
  }

  // ---- epilogue: out = gamma * (acc / l) + x, coalesced via LDS transpose ----
  if (cc == 0) CorrS[qb] = l_run;
  __syncthreads();
  {
    const float4 lv = *(const float4*)&CorrS[qg * 4];
    float linv[4] = {1.f / lv.x, 1.f / lv.y, 1.f / lv.z, 1.f / lv.w};
    #pragma unroll
    for (int j = 0; j < 4; j++)
      #pragma unroll
      for (int i = 0; i < 8; i++)
        Vs[qg * 4 + j][cg * 8 + i] = acc[j][i] * linv[j];
  }
  __syncthreads();
  float gamma = gamma_p[0];
  for (int i = t; i < CC * 16; i += 256) {
    int c = i >> 4, q4 = i & 15;
    size_t base = ((size_t)b * CC + c) * NN + q0 + q4 * 4;
    float4 xv = *(const float4*)&x[base];
    float4 ov;
    ov.x = gamma * Vs[q4 * 4 + 0][c] + xv.x;
    ov.y = gamma * Vs[q4 * 4 + 1][c] + xv.y;
    ov.z = gamma * Vs[q4 * 4 + 2][c] + xv.z;
    ov.w = gamma * Vs[q4 * 4 + 3][c] + xv.w;
    *(float4*)&out[base] = ov;
  }
}

// ---------------------------------------------------------------------------
extern "C" void kernel_launch(void* const* d_in, const int* in_sizes, int n_in,
                              void* d_out, int out_size, void* d_ws, size_t ws_size,
                              hipStream_t stream) {
  const float* x     = (const float*)d_in[0];
  const float* text  = (const float*)d_in[1];
  const float* Wq    = (const float*)d_in[2];
  const float* bq    = (const float*)d_in[3];
  const float* Wk    = (const float*)d_in[4];
  const float* bk    = (const float*)d_in[5];
  const float* Wv    = (const float*)d_in[6];
  const float* bv    = (const float*)d_in[7];
  const float* Wtk   = (const float*)d_in[8];
  const float* btk   = (const float*)d_in[9];
  const float* Wtv   = (const float*)d_in[10];
  const float* btv   = (const float*)d_in[11];
  const float* gamma = (const float*)d_in[12];
  float* outp = (float*)d_out;

  float* ws  = (float*)d_ws;
  float* tkv = ws;
  float* qt  = ws + 1024;
  float* kt  = ws + 1024 + (size_t)BB * NN * C8;
  float* vt  = ws + 1024 + 2 * (size_t)BB * NN * C8;

  k_text<<<BB, 256, 0, stream>>>(text, Wtk, btk, Wtv, btv, tkv);
  k_qkv<<<BB * NN / 64, 256, 0, stream>>>(x, Wq, bq, Wk, bk, Wv, bv, tkv, qt, kt, vt);
  k_attn<<<BB * NN / QB, 256, 0, stream>>>(qt, kt, vt, x, gamma, outp);
}

// Round 3
// 185.008 us; speedup vs baseline: 2.8466x; 2.8466x over previous
//
#include <hip/hip_runtime.h>
#include <math.h>

#define BB 4
#define CC 128
#define C8 16
#define TEXTN 256
#define NN 4096
#define QB 64
#define KB 64

typedef __attribute__((ext_vector_type(8))) __bf16 bf16x8;
typedef __attribute__((ext_vector_type(16))) float f32x16;

static __device__ __forceinline__ ushort f2bf(float f) {
  unsigned u = __builtin_bit_cast(unsigned, f);
  u += 0x7FFFu + ((u >> 16) & 1u);   // RNE (finite values only here)
  return (ushort)(u >> 16);
}

// ---------------------------------------------------------------------------
// Kernel 1: text bias: tk = Wtk@text + btk (16), tv = Wtv@text + btv (128)
__global__ __launch_bounds__(256) void k_text(
    const float* __restrict__ text, const float* __restrict__ Wtk,
    const float* __restrict__ btk, const float* __restrict__ Wtv,
    const float* __restrict__ btv, float* __restrict__ tkv) {
  __shared__ float ts[TEXTN];
  int b = blockIdx.x;
  for (int i = threadIdx.x; i < TEXTN; i += 256) ts[i] = text[b * TEXTN + i];
  __syncthreads();
  int o = threadIdx.x;
  if (o < 144) {
    const float* w;
    float acc;
    if (o < 16) { w = Wtk + o * TEXTN; acc = btk[o]; }
    else        { w = Wtv + (o - 16) * TEXTN; acc = btv[o - 16]; }
    #pragma unroll 8
    for (int t = 0; t < TEXTN; t++) acc += w[t] * ts[t];
    tkv[b * 144 + o] = acc;
  }
}

// ---------------------------------------------------------------------------
// Kernel 2: projections -> bf16. qt[b][n][16], kt[b][n][16], vtT[b][c][n].
__global__ __launch_bounds__(256) void k_qkv(
    const float* __restrict__ x,
    const float* __restrict__ Wq, const float* __restrict__ bq,
    const float* __restrict__ Wk, const float* __restrict__ bk,
    const float* __restrict__ Wv, const float* __restrict__ bv,
    const float* __restrict__ tkv,
    ushort* __restrict__ qt, ushort* __restrict__ kt, ushort* __restrict__ vtT) {
  __shared__ __align__(16) float xs[CC][64];  // 32 KB
  int b = blockIdx.x >> 6;
  int n0 = (blockIdx.x & 63) * 64;
  int t = threadIdx.x;
  const float4* xg = (const float4*)(x + (size_t)b * CC * NN + n0);
  for (int i = t; i < CC * 16; i += 256) {
    int c = i >> 4, n4 = i & 15;
    ((float4*)xs)[c * 16 + n4] = xg[c * (NN / 4) + n4];
  }
  __syncthreads();
  // 160 output channels in 40 groups of 4; og is wave-uniform.
  #pragma unroll
  for (int it = 0; it < 10; ++it) {
    int idx = t + it * 256;
    int og = idx >> 6, nl = idx & 63;
    int n = n0 + nl;
    const float *w0, *w1, *w2, *w3;
    float a0, a1, a2, a3;
    int o0;
    if (og < 4) {
      o0 = og * 4;
      w0 = Wq + (size_t)(o0 + 0) * CC; w1 = Wq + (size_t)(o0 + 1) * CC;
      w2 = Wq + (size_t)(o0 + 2) * CC; w3 = Wq + (size_t)(o0 + 3) * CC;
      a0 = bq[o0 + 0]; a1 = bq[o0 + 1]; a2 = bq[o0 + 2]; a3 = bq[o0 + 3];
    } else if (og < 8) {
      o0 = (og - 4) * 4;
      w0 = Wk + (size_t)(o0 + 0) * CC; w1 = Wk + (size_t)(o0 + 1) * CC;
      w2 = Wk + (size_t)(o0 + 2) * CC; w3 = Wk + (size_t)(o0 + 3) * CC;
      a0 = bk[o0 + 0] + tkv[b * 144 + o0 + 0];
      a1 = bk[o0 + 1] + tkv[b * 144 + o0 + 1];
      a2 = bk[o0 + 2] + tkv[b * 144 + o0 + 2];
      a3 = bk[o0 + 3] + tkv[b * 144 + o0 + 3];
    } else {
      o0 = (og - 8) * 4;
      w0 = Wv + (size_t)(o0 + 0) * CC; w1 = Wv + (size_t)(o0 + 1) * CC;
      w2 = Wv + (size_t)(o0 + 2) * CC; w3 = Wv + (size_t)(o0 + 3) * CC;
      a0 = bv[o0 + 0] + tkv[b * 144 + 16 + o0 + 0];
      a1 = bv[o0 + 1] + tkv[b * 144 + 16 + o0 + 1];
      a2 = bv[o0 + 2] + tkv[b * 144 + 16 + o0 + 2];
      a3 = bv[o0 + 3] + tkv[b * 144 + 16 + o0 + 3];
    }
    #pragma unroll 8
    for (int c = 0; c < CC; ++c) {
      float xv = xs[c][nl];
      a0 = fmaf(w0[c], xv, a0);
      a1 = fmaf(w1[c], xv, a1);
      a2 = fmaf(w2[c], xv, a2);
      a3 = fmaf(w3[c], xv, a3);
    }
    if (og < 4) {
      ushort4 pk; pk.x = f2bf(a0); pk.y = f2bf(a1); pk.z = f2bf(a2); pk.w = f2bf(a3);
      *(ushort4*)&qt[((size_t)b * NN + n) * C8 + o0] = pk;
    } else if (og < 8) {
      ushort4 pk; pk.x = f2bf(a0); pk.y = f2bf(a1); pk.z = f2bf(a2); pk.w = f2bf(a3);
      *(ushort4*)&kt[((size_t)b * NN + n) * C8 + o0] = pk;
    } else {
      vtT[((size_t)b * CC + o0 + 0) * NN + n] = f2bf(a0);
      vtT[((size_t)b * CC + o0 + 1) * NN + n] = f2bf(a1);
      vtT[((size_t)b * CC + o0 + 2) * NN + n] = f2bf(a2);
      vtT[((size_t)b * CC + o0 + 3) * NN + n] = f2bf(a3);
    }
  }
}

// ---------------------------------------------------------------------------
// Kernel 3: flash attention with bf16 MFMA (32x32x16).
// Block: 256 thr = 4 waves, QB=64 queries, loop over 64 key tiles of KB=64.
// Wave roles: wq = w&1 (query half), wh = w>>1 (phase A key half / phase C c-pair).
__global__ __launch_bounds__(256) void k_attn(
    const ushort* __restrict__ qt, const ushort* __restrict__ kt,
    const ushort* __restrict__ vtT, const float* __restrict__ x,
    const float* __restrict__ gamma_p, float* __restrict__ out) {
  __shared__ __align__(16) char smem[43264];
  ushort (*Ks)[16]  = (ushort(*)[16])(smem);           // 2 KB   [m][d]
  ushort (*VsT)[64] = (ushort(*)[64])(smem + 2048);    // 16 KB  [c][m], slot-swizzled
  float  (*ST)[64]  = (float(*)[64])(smem + 18432);    // 16 KB  [q][m^((q&7)<<2)]
  ushort (*PS)[64]  = (ushort(*)[64])(smem + 34816);   // 8 KB   [q][m], slot-swizzled
  float  *CorrS     = (float*)(smem + 43008);          // 256 B  (not overlapped by Ws)
  float  (*Ws)[133] = (float(*)[133])(smem);           // 34 KB  epilogue overlay

  int b = blockIdx.x >> 6;
  int q0 = (blockIdx.x & 63) * QB;
  int t = threadIdx.x;
  int w = t >> 6, lane = t & 63;
  int wq = w & 1, wh = w >> 1;
  int l31 = lane & 31, hi = lane >> 5;
  int qb = t >> 2, cc2 = t & 3;

  // Q fragment: A-operand of 32x32x16 (row = l31, k = hi*8+j), held all kernel.
  bf16x8 aq = *(const bf16x8*)&qt[((size_t)b * NN + q0 + wq * 32 + l31) * C8 + hi * 8];

  f32x16 acc0, acc1;
  #pragma unroll
  for (int r = 0; r < 16; ++r) { acc0[r] = 0.f; acc1[r] = 0.f; }
  float m_run = -INFINITY, l_run = 0.f;

  for (int kb = 0; kb < NN / KB; ++kb) {
    int m0 = kb * KB;
    // ---- stage K (2 KB flat) and V^T (16 KB, slot-swizzled) ----
    if (t < 128)
      ((uint4*)Ks)[t] = ((const uint4*)(kt + ((size_t)b * NN + m0) * C8))[t];
    {
      const ushort* vbase = vtT + (size_t)b * CC * NN + m0;
      #pragma unroll
      for (int p = 0; p < 4; ++p) {
        int idx = t + p * 256;
        int c = idx >> 3, s = idx & 7;
        uint4 vv = *(const uint4*)(vbase + (size_t)c * NN + s * 8);
        *(uint4*)&VsT[c][(s ^ (c & 7)) * 8] = vv;
      }
    }
    __syncthreads();

    // ---- phase A: S[q][m] = q.k via one MFMA per wave ----
    {
      int m = l31 + 32 * wh;
      bf16x8 bk = *(const bf16x8*)&Ks[m][hi * 8];
      f32x16 z;
      #pragma unroll
      for (int r = 0; r < 16; ++r) z[r] = 0.f;
      f32x16 s16 = __builtin_amdgcn_mfma_f32_32x32x16_bf16(aq, bk, z, 0, 0, 0);
      #pragma unroll
      for (int r = 0; r < 16; ++r) {
        int q = (r & 3) + 8 * (r >> 2) + 4 * hi + 32 * wq;
        ST[q][m ^ ((q & 7) << 2)] = s16[r];
      }
    }
    __syncthreads();

    // ---- phase B: online softmax (thread = (q row, m quarter)) ----
    {
      float sv[16];
      float mx = -INFINITY;
      #pragma unroll
      for (int j = 0; j < 16; ++j) {
        sv[j] = ST[qb][(4 * j + cc2) ^ ((qb & 7) << 2)];
        mx = fmaxf(mx, sv[j]);
      }
      mx = fmaxf(mx, __shfl_xor(mx, 1));
      mx = fmaxf(mx, __shfl_xor(mx, 2));
      float nm = fmaxf(m_run, mx);
      float corr = __expf(m_run - nm);
      float ps = 0.f;
      #pragma unroll
      for (int j = 0; j < 16; ++j) {
        float p = __expf(sv[j] - nm);
        ps += p;
        int m = 4 * j + cc2;
        PS[qb][((m >> 3) ^ (qb & 7)) * 8 + (m & 7)] = f2bf(p);
      }
      ps += __shfl_xor(ps, 1);
      ps += __shfl_xor(ps, 2);
      l_run = l_run * corr + ps;
      m_run = nm;
      if (cc2 == 0) CorrS[qb] = corr;
    }
    __syncthreads();

    // ---- phase C: acc = acc*corr + P V (8 MFMAs per wave) ----
    {
      float corr16[16];
      #pragma unroll
      for (int r = 0; r < 16; ++r)
        corr16[r] = CorrS[(r & 3) + 8 * (r >> 2) + 4 * hi + 32 * wq];
      #pragma unroll
      for (int r = 0; r < 16; ++r) { acc0[r] *= corr16[r]; acc1[r] *= corr16[r]; }
      int qrow = l31 + 32 * wq;
      int c0 = wh * 64 + l31;
      int c1 = wh * 64 + 32 + l31;
      #pragma unroll
      for (int st = 0; st < 4; ++st) {
        bf16x8 ap  = *(const bf16x8*)&PS[qrow][((st * 2 + hi) ^ (qrow & 7)) * 8];
        bf16x8 bv0 = *(const bf16x8*)&VsT[c0][((st * 2 + hi) ^ (c0 & 7)) * 8];
        acc0 = __builtin_amdgcn_mfma_f32_32x32x16_bf16(ap, bv0, acc0, 0, 0, 0);
        bf16x8 bv1 = *(const bf16x8*)&VsT[c1][((st * 2 + hi) ^ (c1 & 7)) * 8];
        acc1 = __builtin_amdgcn_mfma_f32_32x32x16_bf16(ap, bv1, acc1, 0, 0, 0);
      }
    }
    __syncthreads();
  }

  // ---- epilogue: out = gamma * acc/l + x ----
  if (cc2 == 0) CorrS[qb] = l_run;
  __syncthreads();
  {
    #pragma unroll
    for (int r = 0; r < 16; ++r) {
      int q = (r & 3) + 8 * (r >> 2) + 4 * hi + 32 * wq;
      float linv = 1.f / CorrS[q];
      Ws[q][wh * 64 + l31]      = acc0[r] * linv;
      Ws[q][wh * 64 + 32 + l31] = acc1[r] * linv;
    }
  }
  __syncthreads();
  float gamma = gamma_p[0];
  for (int i = t; i < CC * 16; i += 256) {
    int c = i >> 4, q4 = i & 15;
    size_t base = ((size_t)b * CC + c) * NN + q0 + q4 * 4;
    float4 xv = *(const float4*)&x[base];
    float4 ov;
    ov.x = gamma * Ws[q4 * 4 + 0][c] + xv.x;
    ov.y = gamma * Ws[q4 * 4 + 1][c] + xv.y;
    ov.z = gamma * Ws[q4 * 4 + 2][c] + xv.z;
    ov.w = gamma * Ws[q4 * 4 + 3][c] + xv.w;
    *(float4*)&out[base] = ov;
  }
}

// ---------------------------------------------------------------------------
extern "C" void kernel_launch(void* const* d_in, const int* in_sizes, int n_in,
                              void* d_out, int out_size, void* d_ws, size_t ws_size,
                              hipStream_t stream) {
  const float* x     = (const float*)d_in[0];
  const float* text  = (const float*)d_in[1];
  const float* Wq    = (const float*)d_in[2];
  const float* bq    = (const float*)d_in[3];
  const float* Wk    = (const float*)d_in[4];
  const float* bk    = (const float*)d_in[5];
  const float* Wv    = (const float*)d_in[6];
  const float* bv    = (const float*)d_in[7];
  const float* Wtk   = (const float*)d_in[8];
  const float* btk   = (const float*)d_in[9];
  const float* Wtv   = (const float*)d_in[10];
  const float* btv   = (const float*)d_in[11];
  const float* gamma = (const float*)d_in[12];
  float* outp = (float*)d_out;

  char* wsb = (char*)d_ws;
  float*  tkv = (float*)wsb;                                   // 2304 B
  ushort* qt  = (ushort*)(wsb + 4096);                         // 512 KB
  ushort* kt  = (ushort*)(wsb + 4096 + 524288);                // 512 KB
  ushort* vtT = (ushort*)(wsb + 4096 + 2 * 524288);            // 4 MB

  k_text<<<BB, 256, 0, stream>>>(text, Wtk, btk, Wtv, btv, tkv);
  k_qkv<<<BB * NN / 64, 256, 0, stream>>>(x, Wq, bq, Wk, bk, Wv, bv, tkv, qt, kt, vtT);
  k_attn<<<BB * NN / QB, 256, 0, stream>>>(qt, kt, vtT, x, gamma, outp);
}

// Round 4
// 57.245 us; speedup vs baseline: 9.1997x; 3.2319x over previous
//
#include <hip/hip_runtime.h>
#include <math.h>

#define BB 4
#define CC 128
#define C8 16
#define TEXTN 256
#define NN 4096
#define WQB 32        // queries per k_attn block

typedef __attribute__((ext_vector_type(8))) __bf16 bf16x8;
typedef __attribute__((ext_vector_type(16))) float f32x16;

static __device__ __forceinline__ ushort f2bf(float f) {
  unsigned u = __builtin_bit_cast(unsigned, f);
  u += 0x7FFFu + ((u >> 16) & 1u);
  return (ushort)(u >> 16);
}

static __device__ __forceinline__ unsigned cvt_pk_bf16(float lo, float hi) {
  unsigned r;
  asm("v_cvt_pk_bf16_f32 %0, %1, %2" : "=v"(r) : "v"(lo), "v"(hi));
  return r;
}
// x' = {lanes<32: x; lanes>=32: y[lane-32]}, y' = {lanes<32: x[lane+32]; lanes>=32: y}
static __device__ __forceinline__ void pl32swap(unsigned &a, unsigned &b) {
  asm("v_permlane32_swap_b32 %0, %1" : "+v"(a), "+v"(b));
}

// ---------------------------------------------------------------------------
// Kernel 1: text bias
__global__ __launch_bounds__(256) void k_text(
    const float* __restrict__ text, const float* __restrict__ Wtk,
    const float* __restrict__ btk, const float* __restrict__ Wtv,
    const float* __restrict__ btv, float* __restrict__ tkv) {
  __shared__ float ts[TEXTN];
  int b = blockIdx.x;
  for (int i = threadIdx.x; i < TEXTN; i += 256) ts[i] = text[b * TEXTN + i];
  __syncthreads();
  int o = threadIdx.x;
  if (o < 144) {
    const float* w;
    float acc;
    if (o < 16) { w = Wtk + o * TEXTN; acc = btk[o]; }
    else        { w = Wtv + (o - 16) * TEXTN; acc = btv[o - 16]; }
    #pragma unroll 8
    for (int t = 0; t < TEXTN; t++) acc += w[t] * ts[t];
    tkv[b * 144 + o] = acc;
  }
}

// ---------------------------------------------------------------------------
// Kernel 2: MFMA projections. 320 thr = 5 waves. Wave 0 -> q|k rows, waves 1-4
// -> v-blocks. Outputs: qt[b][n][16], kt[b][n][16], vtB[b][n/8][128][8] (bf16).
__global__ __launch_bounds__(320) void k_qkv(
    const float* __restrict__ x,
    const float* __restrict__ Wq, const float* __restrict__ bq,
    const float* __restrict__ Wk, const float* __restrict__ bk,
    const float* __restrict__ Wv, const float* __restrict__ bv,
    const float* __restrict__ tkv,
    ushort* __restrict__ qt, ushort* __restrict__ kt, ushort* __restrict__ vtB) {
  __shared__ __align__(16) ushort xs[64 * 128];  // 16 KB, [n][c] chunk-swizzled
  int b = blockIdx.x >> 6;
  int n0 = (blockIdx.x & 63) * 64;
  int t = threadIdx.x;
  int w = t >> 6, lane = t & 63, l31 = lane & 31, hi = lane >> 5;

  // stage x tile -> bf16 LDS, swizzled: [n][chunk' = (c>>3)^(n&15)][c&7]
  for (int i = t; i < 2048; i += 320) {
    int c = i >> 4, n4 = i & 15;
    float4 xv = *(const float4*)&x[((size_t)b * CC + c) * NN + n0 + n4 * 4];
    float vals[4] = {xv.x, xv.y, xv.z, xv.w};
    #pragma unroll
    for (int k = 0; k < 4; ++k) {
      int n = n4 * 4 + k;
      xs[n * 128 + ((((c >> 3) ^ (n & 15)) << 3) | (c & 7))] = f2bf(vals[k]);
    }
  }

  // W A-fragments (8 k-slices of 16), rows: wave0 = q0..15|k0..15, waves1-4 = v
  const float* wrow;
  if (w == 0) wrow = (l31 < 16) ? (Wq + l31 * CC) : (Wk + (l31 - 16) * CC);
  else        wrow = Wv + (size_t)(32 * (w - 1) + l31) * CC;
  bf16x8 af[8];
  #pragma unroll
  for (int ks = 0; ks < 8; ++ks) {
    float4 u0 = *(const float4*)&wrow[ks * 16 + hi * 8];
    float4 u1 = *(const float4*)&wrow[ks * 16 + hi * 8 + 4];
    union { ushort u[8]; bf16x8 v; } tmp;
    tmp.u[0] = f2bf(u0.x); tmp.u[1] = f2bf(u0.y); tmp.u[2] = f2bf(u0.z); tmp.u[3] = f2bf(u0.w);
    tmp.u[4] = f2bf(u1.x); tmp.u[5] = f2bf(u1.y); tmp.u[6] = f2bf(u1.z); tmp.u[7] = f2bf(u1.w);
    af[ks] = tmp.v;
  }
  // bias per output row (16 rows per lane)
  float badd[16];
  #pragma unroll
  for (int r = 0; r < 16; ++r) {
    int ol = (r & 3) + 8 * (r >> 2) + 4 * hi;
    if (w == 0) badd[r] = (ol < 16) ? bq[ol] : (bk[ol - 16] + tkv[b * 144 + ol - 16]);
    else { int c = 32 * (w - 1) + ol; badd[r] = bv[c] + tkv[b * 144 + 16 + c]; }
  }
  __syncthreads();

  #pragma unroll
  for (int n32 = 0; n32 < 2; ++n32) {
    int n = n32 * 32 + l31;
    int ng = n0 + n;
    bf16x8 bf[8];
    #pragma unroll
    for (int ks = 0; ks < 8; ++ks)
      bf[ks] = *(const bf16x8*)&xs[n * 128 + (((ks * 2 + hi) ^ (n & 15)) << 3)];
    f32x16 d;
    #pragma unroll
    for (int r = 0; r < 16; ++r) d[r] = 0.f;
    #pragma unroll
    for (int ks = 0; ks < 8; ++ks)
      d = __builtin_amdgcn_mfma_f32_32x32x16_bf16(af[ks], bf[ks], d, 0, 0, 0);
    #pragma unroll
    for (int g = 0; g < 4; ++g) {
      int o0 = 8 * g + 4 * hi;
      ushort4 pkv;
      pkv.x = f2bf(d[g * 4 + 0] + badd[g * 4 + 0]);
      pkv.y = f2bf(d[g * 4 + 1] + badd[g * 4 + 1]);
      pkv.z = f2bf(d[g * 4 + 2] + badd[g * 4 + 2]);
      pkv.w = f2bf(d[g * 4 + 3] + badd[g * 4 + 3]);
      if (w == 0) {
        if (o0 < 16) *(ushort4*)&qt[(b * NN + ng) * C8 + o0] = pkv;
        else         *(ushort4*)&kt[(b * NN + ng) * C8 + o0 - 16] = pkv;
      } else {
        int c0 = 32 * (w - 1) + o0;
        int base = b * (NN / 8) * CC * 8 + (ng >> 3) * (CC * 8) + (ng & 7);
        vtB[base + (c0 + 0) * 8] = pkv.x;
        vtB[base + (c0 + 1) * 8] = pkv.y;
        vtB[base + (c0 + 2) * 8] = pkv.z;
        vtB[base + (c0 + 3) * 8] = pkv.w;
      }
    }
  }
}

// ---------------------------------------------------------------------------
// Kernel 3: flash attention, no LDS / no barriers in the main loop.
// Grid: BB * (NN/32) = 512 blocks, 256 thr = 4 waves. Wave w owns the m-slice
// {t*128 + w*32 .. +32} per iteration; 4-way merge in the epilogue.
__global__ __launch_bounds__(256) void k_attn(
    const ushort* __restrict__ qt, const ushort* __restrict__ kt,
    const ushort* __restrict__ vtB, const float* __restrict__ x,
    const float* __restrict__ gamma_p, float* __restrict__ out) {
  __shared__ __align__(16) float mergeAcc[4][1024];  // 16 KB
  __shared__ float mergeML[2][4][32];
  __shared__ float invGL[32];

  int b = blockIdx.x >> 7;
  int q0 = (blockIdx.x & 127) * WQB;
  int t = threadIdx.x;
  int w = t >> 6, lane = t & 63, l31 = lane & 31, hi = lane >> 5;

  const ushort* ktb = kt + (size_t)b * NN * C8;
  const ushort* vb  = vtB + (size_t)b * (NN / 8) * CC * 8;

  // Q B-fragment (col = l31, k = hi*8+j), held all kernel
  bf16x8 qf = *(const bf16x8*)&qt[((size_t)b * NN + q0 + l31) * C8 + hi * 8];

  f32x16 acc[4];
  #pragma unroll
  for (int cb = 0; cb < 4; ++cb)
    #pragma unroll
    for (int r = 0; r < 16; ++r) acc[cb][r] = 0.f;
  float m_run = -INFINITY, l_run = 0.f;

  bf16x8 kfA, kfB, vfA[8], vfB[8];

#define LDK(TT) (*(const bf16x8*)&ktb[(((TT) * 128 + w * 32 + l31)) * C8 + hi * 8])
#define LDV(TT, CB, KS) (*(const bf16x8*)&vb[(size_t)((TT) * 16 + w * 4 + (KS) * 2 + hi) * (CC * 8) + ((CB) * 32 + l31) * 8])

  kfA = LDK(0);
  #pragma unroll
  for (int cb = 0; cb < 4; ++cb) {
    vfA[cb * 2 + 0] = LDV(0, cb, 0);
    vfA[cb * 2 + 1] = LDV(0, cb, 1);
  }

#define STEP(CK, CV, NK, NV, TT)                                              \
  {                                                                           \
    int tn = ((TT) + 1) & 31;                                                 \
    NK = LDK(tn);                                                             \
    _Pragma("unroll")                                                         \
    for (int cb = 0; cb < 4; ++cb) {                                          \
      NV[cb * 2 + 0] = LDV(tn, cb, 0);                                        \
      NV[cb * 2 + 1] = LDV(tn, cb, 1);                                        \
    }                                                                         \
    f32x16 z;                                                                 \
    _Pragma("unroll")                                                         \
    for (int r = 0; r < 16; ++r) z[r] = 0.f;                                  \
    f32x16 s = __builtin_amdgcn_mfma_f32_32x32x16_bf16(CK, qf, z, 0, 0, 0);   \
    float mx = s[0];                                                          \
    _Pragma("unroll")                                                         \
    for (int r = 1; r < 16; ++r) mx = fmaxf(mx, s[r]);                        \
    mx = fmaxf(mx, __shfl_xor(mx, 32));                                       \
    bool resc = __any(mx > m_run + 8.f);                                      \
    float nm = m_run, corr = 1.f;                                             \
    if (resc) { nm = fmaxf(m_run, mx); corr = __expf(m_run - nm); }           \
    float p[16], ps = 0.f;                                                    \
    _Pragma("unroll")                                                         \
    for (int r = 0; r < 16; ++r) { p[r] = __expf(s[r] - nm); ps += p[r]; }    \
    ps += __shfl_xor(ps, 32);                                                 \
    if (resc) {                                                               \
      l_run *= corr;                                                          \
      _Pragma("unroll")                                                       \
      for (int cb = 0; cb < 4; ++cb)                                          \
        _Pragma("unroll")                                                     \
        for (int r = 0; r < 16; ++r) acc[cb][r] *= corr;                      \
      m_run = nm;                                                             \
    }                                                                         \
    l_run += ps;                                                              \
    bf16x8 pf0, pf1;                                                          \
    {                                                                         \
      unsigned a0 = cvt_pk_bf16(p[0], p[1]), b0 = cvt_pk_bf16(p[4], p[5]);    \
      unsigned c0 = cvt_pk_bf16(p[2], p[3]), d0 = cvt_pk_bf16(p[6], p[7]);    \
      pl32swap(a0, b0); pl32swap(c0, d0);                                     \
      union { unsigned u[4]; bf16x8 v; } u0; u0.u[0] = a0; u0.u[1] = c0;      \
      u0.u[2] = b0; u0.u[3] = d0; pf0 = u0.v;                                 \
      unsigned a1 = cvt_pk_bf16(p[8], p[9]), b1 = cvt_pk_bf16(p[12], p[13]);  \
      unsigned c1 = cvt_pk_bf16(p[10], p[11]), d1 = cvt_pk_bf16(p[14], p[15]);\
      pl32swap(a1, b1); pl32swap(c1, d1);                                     \
      union { unsigned u[4]; bf16x8 v; } u1; u1.u[0] = a1; u1.u[1] = c1;      \
      u1.u[2] = b1; u1.u[3] = d1; pf1 = u1.v;                                 \
    }                                                                         \
    _Pragma("unroll")                                                         \
    for (int cb = 0; cb < 4; ++cb) {                                          \
      acc[cb] = __builtin_amdgcn_mfma_f32_32x32x16_bf16(CV[cb * 2 + 0], pf0, acc[cb], 0, 0, 0); \
      acc[cb] = __builtin_amdgcn_mfma_f32_32x32x16_bf16(CV[cb * 2 + 1], pf1, acc[cb], 0, 0, 0); \
    }                                                                         \
  }

  for (int tt = 0; tt < 32; tt += 2) {
    STEP(kfA, vfA, kfB, vfB, tt)
    STEP(kfB, vfB, kfA, vfA, tt + 1)
  }
#undef STEP
#undef LDK
#undef LDV

  // ---- 4-way merge across waves + epilogue ----
  if (hi == 0) { mergeML[0][w][l31] = m_run; mergeML[1][w][l31] = l_run; }
  __syncthreads();
  float M = mergeML[0][0][l31];
  #pragma unroll
  for (int ww = 1; ww < 4; ++ww) M = fmaxf(M, mergeML[0][ww][l31]);
  float L = 0.f;
  #pragma unroll
  for (int ww = 0; ww < 4; ++ww)
    L += mergeML[1][ww][l31] * __expf(mergeML[0][ww][l31] - M);
  float scale = __expf(m_run - M);
  if (w == 0 && hi == 0) invGL[l31] = gamma_p[0] / L;

  int d0 = t * 4;
  int clocal = d0 >> 5, qq = d0 & 31;
  #pragma unroll
  for (int cb = 0; cb < 4; ++cb) {
    #pragma unroll
    for (int r = 0; r < 16; ++r)
      mergeAcc[w][((r & 3) + 8 * (r >> 2) + 4 * hi) * 32 + l31] = acc[cb][r] * scale;
    __syncthreads();
    float4 s0 = *(const float4*)&mergeAcc[0][d0];
    float4 s1 = *(const float4*)&mergeAcc[1][d0];
    float4 s2 = *(const float4*)&mergeAcc[2][d0];
    float4 s3 = *(const float4*)&mergeAcc[3][d0];
    float4 gl = *(const float4*)&invGL[qq];
    int c = cb * 32 + clocal;
    size_t base = ((size_t)b * CC + c) * NN + q0 + qq;
    float4 xv = *(const float4*)&x[base];
    float4 ov;
    ov.x = (s0.x + s1.x + s2.x + s3.x) * gl.x + xv.x;
    ov.y = (s0.y + s1.y + s2.y + s3.y) * gl.y + xv.y;
    ov.z = (s0.z + s1.z + s2.z + s3.z) * gl.z + xv.z;
    ov.w = (s0.w + s1.w + s2.w + s3.w) * gl.w + xv.w;
    *(float4*)&out[base] = ov;
    __syncthreads();
  }
}

// ---------------------------------------------------------------------------
extern "C" void kernel_launch(void* const* d_in, const int* in_sizes, int n_in,
                              void* d_out, int out_size, void* d_ws, size_t ws_size,
                              hipStream_t stream) {
  const float* x     = (const float*)d_in[0];
  const float* text  = (const float*)d_in[1];
  const float* Wq    = (const float*)d_in[2];
  const float* bq    = (const float*)d_in[3];
  const float* Wk    = (const float*)d_in[4];
  const float* bk    = (const float*)d_in[5];
  const float* Wv    = (const float*)d_in[6];
  const float* bv    = (const float*)d_in[7];
  const float* Wtk   = (const float*)d_in[8];
  const float* btk   = (const float*)d_in[9];
  const float* Wtv   = (const float*)d_in[10];
  const float* btv   = (const float*)d_in[11];
  const float* gamma = (const float*)d_in[12];
  float* outp = (float*)d_out;

  char* wsb = (char*)d_ws;
  float*  tkv = (float*)wsb;                               // 2.3 KB
  ushort* qt  = (ushort*)(wsb + 4096);                     // 512 KB
  ushort* kt  = (ushort*)(wsb + 4096 + 524288);            // 512 KB
  ushort* vtB = (ushort*)(wsb + 4096 + 2 * 524288);        // 4 MB

  k_text<<<BB, 256, 0, stream>>>(text, Wtk, btk, Wtv, btv, tkv);
  k_qkv<<<BB * NN / 64, 320, 0, stream>>>(x, Wq, bq, Wk, bk, Wv, bv, tkv, qt, kt, vtB);
  k_attn<<<BB * NN / WQB, 256, 0, stream>>>(qt, kt, vtB, x, gamma, outp);
}